// Round 1
// baseline (287.660 us; speedup 1.0000x reference)
//
#include <hip/hip_runtime.h>

#define UNITS 20

__device__ __forceinline__ float rcpf_fast(float x) { return __builtin_amdgcn_rcpf(x); }
__device__ __forceinline__ float sigmoidf_fast(float x) { return rcpf_fast(1.0f + __expf(-x)); }
// tanh(x) = 1 - 2/(exp(2x)+1); stable: x>>0 -> exp=inf -> 1; x<<0 -> exp=0 -> -1
__device__ __forceinline__ float tanhf_fast(float x) { return 1.0f - 2.0f * rcpf_fast(1.0f + __expf(2.0f * x)); }

__global__ __launch_bounds__(256) void stn_gpe_kernel(
    const float* __restrict__ x, const float* __restrict__ h, const float* __restrict__ c,
    const float* __restrict__ W_ih, const float* __restrict__ W_hh,
    const float* __restrict__ b_ih, const float* __restrict__ b_hh,
    const float* __restrict__ W_lat, float* __restrict__ out, int B) {
  int t = blockIdx.x * blockDim.x + threadIdx.x;
  if (t >= B) return;

  const size_t base = (size_t)t * UNITS;
  const float4* x4 = reinterpret_cast<const float4*>(x + base);
  const float4* h4 = reinterpret_cast<const float4*>(h + base);

  float xv[UNITS], hv[UNITS];
#pragma unroll
  for (int i = 0; i < 5; ++i) {
    float4 a = x4[i];
    xv[4 * i + 0] = a.x; xv[4 * i + 1] = a.y; xv[4 * i + 2] = a.z; xv[4 * i + 3] = a.w;
    float4 b = h4[i];
    hv[4 * i + 0] = b.x; hv[4 * i + 1] = b.y; hv[4 * i + 2] = b.z; hv[4 * i + 3] = b.w;
  }

  // lateral accumulators (h_lstm @ W_lat.T), filled on the fly
  float lat[UNITS];
#pragma unroll
  for (int v = 0; v < UNITS; ++v) lat[v] = 0.0f;

  float* outh = out;                       // h_next [B, UNITS]
  float* outc = out + (size_t)B * UNITS;   // c_next [B, UNITS]

  // Two units per iteration: 8 gate accumulators (i,f,g,o) x (u, u+1).
#pragma unroll 2
  for (int u = 0; u < UNITS; u += 2) {
    float acc[8];
#pragma unroll
    for (int q = 0; q < 8; ++q) {
      int row = (q >> 1) * UNITS + u + (q & 1);   // gate-major rows: i,f,g,o
      acc[q] = b_ih[row] + b_hh[row];             // wave-uniform -> s_load
    }
#pragma unroll
    for (int k = 0; k < UNITS; ++k) {
      float xk = xv[k], hk = hv[k];
#pragma unroll
      for (int q = 0; q < 8; ++q) {
        int row = (q >> 1) * UNITS + u + (q & 1);
        acc[q] = fmaf(W_ih[row * UNITS + k], xk, acc[q]);  // s_w * v_x
        acc[q] = fmaf(W_hh[row * UNITS + k], hk, acc[q]);
      }
    }

    float2 cc = *reinterpret_cast<const float2*>(c + base + u);
    float cin0 = cc.x, cin1 = cc.y;

    float cn[2], hl[2];
#pragma unroll
    for (int d = 0; d < 2; ++d) {
      float ig = sigmoidf_fast(acc[0 + d]);
      float fg = sigmoidf_fast(acc[2 + d]);
      float gg = tanhf_fast(acc[4 + d]);
      float og = sigmoidf_fast(acc[6 + d]);
      float cv = (d == 0) ? cin0 : cin1;
      float cnv = fg * cv + ig * gg;
      cn[d] = cnv;
      hl[d] = og * tanhf_fast(cnv);
    }

    *reinterpret_cast<float2*>(outc + base + u) = make_float2(cn[0], cn[1]);

#pragma unroll
    for (int v = 0; v < UNITS; ++v) {
      lat[v] = fmaf(W_lat[v * UNITS + u + 0], hl[0], lat[v]);
      lat[v] = fmaf(W_lat[v * UNITS + u + 1], hl[1], lat[v]);
    }
  }

  float hn[UNITS];
#pragma unroll
  for (int v = 0; v < UNITS; ++v) hn[v] = tanhf_fast(lat[v]);

  float4* oh4 = reinterpret_cast<float4*>(outh + base);
#pragma unroll
  for (int i = 0; i < 5; ++i)
    oh4[i] = make_float4(hn[4 * i + 0], hn[4 * i + 1], hn[4 * i + 2], hn[4 * i + 3]);
}

extern "C" void kernel_launch(void* const* d_in, const int* in_sizes, int n_in,
                              void* d_out, int out_size, void* d_ws, size_t ws_size,
                              hipStream_t stream) {
  const float* x     = (const float*)d_in[0];
  const float* h     = (const float*)d_in[1];
  const float* c     = (const float*)d_in[2];
  const float* W_ih  = (const float*)d_in[3];
  const float* W_hh  = (const float*)d_in[4];
  const float* b_ih  = (const float*)d_in[5];
  const float* b_hh  = (const float*)d_in[6];
  const float* W_lat = (const float*)d_in[7];
  float* out = (float*)d_out;

  int B = in_sizes[0] / UNITS;
  int block = 256;
  int grid = (B + block - 1) / block;
  stn_gpe_kernel<<<grid, block, 0, stream>>>(x, h, c, W_ih, W_hh, b_ih, b_hh, W_lat, out, B);
}

// Round 2
// 260.645 us; speedup vs baseline: 1.1036x; 1.1036x over previous
//
#include <hip/hip_runtime.h>

#define UNITS 20

typedef __attribute__((ext_vector_type(8))) short short8;
typedef __attribute__((ext_vector_type(4))) float floatx4;
typedef unsigned int u32;
typedef unsigned short u16;

__device__ __forceinline__ float rcpf_fast(float x) { return __builtin_amdgcn_rcpf(x); }
__device__ __forceinline__ float sigmoidf_fast(float x) { return rcpf_fast(1.0f + __expf(-x)); }
__device__ __forceinline__ float tanhf_fast(float x) { return 1.0f - 2.0f * rcpf_fast(1.0f + __expf(2.0f * x)); }

__device__ __forceinline__ u16 f2bf(float f) {
  u32 u = __builtin_bit_cast(u32, f);
  u += 0x7fffu + ((u >> 16) & 1u);   // round-to-nearest-even
  return (u16)(u >> 16);
}

// ---------------------------------------------------------------------------
// Prep kernel: pack W = [W_ih | W_hh] (80 x 40, K-padded to 64) into the exact
// B-operand lane layout of mfma_f32_16x16x32_bf16:
//   frag[t][c]: lane holds B[k = c*32 + (lane>>4)*8 + j][n = t*16 + (lane&15)]
//   where B[k][n] = W[n][k]  (gates = Z @ W^T).
// Also fuse bias = b_ih + b_hh.
// ---------------------------------------------------------------------------
__global__ void prep_kernel(const float* __restrict__ W_ih, const float* __restrict__ W_hh,
                            const float* __restrict__ b_ih, const float* __restrict__ b_hh,
                            u16* __restrict__ frags, float* __restrict__ bias) {
  int tid = threadIdx.x;
  for (int e = tid; e < 640; e += 256) {   // 10 frags * 64 lanes
    int fi = e >> 6, lane = e & 63;
    int t = fi >> 1, cc = fi & 1;
    int n = t * 16 + (lane & 15);
    int q = lane >> 4;
    short8 v8;
#pragma unroll
    for (int j = 0; j < 8; ++j) {
      int k = cc * 32 + q * 8 + j;
      float v = 0.0f;
      if (k < 20) v = W_ih[n * UNITS + k];
      else if (k < 40) v = W_hh[n * UNITS + (k - 20)];
      v8[j] = (short)f2bf(v);
    }
    *(short8*)(frags + (size_t)e * 8) = v8;
  }
  if (tid < 80) bias[tid] = b_ih[tid] + b_hh[tid];
}

// ---------------------------------------------------------------------------
// Main kernel: 256 threads = 4 waves; block handles 64 batch rows (16/wave).
// ---------------------------------------------------------------------------
#define SZ 88   // Zs stride in bf16 elems (16B-aligned rows, ~2-way banks)
#define SG 81   // gate stride in f32 (odd mult -> conflict-light)
#define SH 21   // h_lstm stride in f32

__global__ __launch_bounds__(256) void stn_main(
    const float* __restrict__ x, const float* __restrict__ h, const float* __restrict__ c,
    const u16* __restrict__ frags, const float* __restrict__ bias,
    const float* __restrict__ W_lat, float* __restrict__ out, int B) {
  __shared__ u16 Zs[64 * SZ];    // [x | h | 0-pad] bf16, K = 64
  __shared__ float Gs[64 * SG];  // gates f32 (80 used per row)
  __shared__ float Hs[64 * SH];  // h_lstm f32 (20 used per row)

  const int tid = threadIdx.x;
  const int lane = tid & 63;
  const int wv = tid >> 6;       // wave id 0..3
  const int r = tid & 63;        // row-in-block for staging/epilogue
  const int s = tid >> 6;        // segment 0..3
  const long rowBase = (long)blockIdx.x * 64;
  const long rg = rowBase + r;
  const long rgc = rg < B ? rg : (long)(B - 1);  // clamped for loads
  const bool live = rg < B;

  // zero-fill K pad (k = 40..63): each thread zeroes 6 elems of its row
  {
    u16* zp = Zs + r * SZ + 40 + s * 6;
#pragma unroll
    for (int i = 0; i < 6; ++i) zp[i] = 0;
  }
  // stage x (k 0..19) and h (k 20..39) as bf16
  {
    const float* src = (s < 2) ? x : h;
    int colb = (s & 1) * 10;
    int kb = (s < 2 ? 0 : 20) + colb;
    const float2* p = (const float2*)(src + rgc * UNITS + colb);
    u32* zp = (u32*)(Zs + r * SZ + kb);   // kb even -> 4B aligned
#pragma unroll
    for (int i = 0; i < 5; ++i) {
      float2 v = p[i];
      zp[i] = (u32)f2bf(v.x) | ((u32)f2bf(v.y) << 16);
    }
  }
  __syncthreads();

  // ---- gate GEMM on MFMA ----
  floatx4 acc[5];
  {
    const int m = lane & 15, q = lane >> 4;
    short8 afrag[2];
#pragma unroll
    for (int cc = 0; cc < 2; ++cc)
      afrag[cc] = *(const short8*)(Zs + (wv * 16 + m) * SZ + cc * 32 + q * 8);
#pragma unroll
    for (int t = 0; t < 5; ++t) {
      float bv = bias[t * 16 + m];
      acc[t] = (floatx4){bv, bv, bv, bv};
#pragma unroll
      for (int cc = 0; cc < 2; ++cc) {
        short8 bfrag = *(const short8*)(frags + ((size_t)(t * 2 + cc) * 64 + lane) * 8);
        acc[t] = __builtin_amdgcn_mfma_f32_16x16x32_bf16(afrag[cc], bfrag, acc[t], 0, 0, 0);
      }
    }
    // scatter C/D (col = lane&15, row = q*4 + reg) into gate LDS
#pragma unroll
    for (int t = 0; t < 5; ++t) {
      int n = t * 16 + m;
#pragma unroll
      for (int reg = 0; reg < 4; ++reg) {
        int rb = wv * 16 + q * 4 + reg;
        Gs[rb * SG + n] = acc[t][reg];
      }
    }
  }
  __syncthreads();

  // ---- LSTM pointwise: 5 (row,unit) pairs per thread ----
  {
    int ub = s * 5;
    const float* cp = c + rgc * UNITS + ub;
    float* outc = out + (long)B * UNITS + rg * UNITS + ub;
#pragma unroll
    for (int i = 0; i < 5; ++i) {
      int u = ub + i;
      float ig = sigmoidf_fast(Gs[r * SG + u]);
      float fg = sigmoidf_fast(Gs[r * SG + 20 + u]);
      float gg = tanhf_fast(Gs[r * SG + 40 + u]);
      float og = sigmoidf_fast(Gs[r * SG + 60 + u]);
      float cn = fg * cp[i] + ig * gg;
      if (live) outc[i] = cn;
      Hs[r * SH + u] = og * tanhf_fast(cn);
    }
  }
  __syncthreads();

  // ---- lateral: h_next = tanh(h_lstm @ W_lat^T), 5 out-units per thread ----
  {
    int vb = s * 5;
    float hl[UNITS];
#pragma unroll
    for (int u = 0; u < UNITS; ++u) hl[u] = Hs[r * SH + u];
    float* outh = out + rg * UNITS + vb;
#pragma unroll
    for (int i = 0; i < 5; ++i) {
      int v = vb + i;
      float a = 0.0f;
#pragma unroll
      for (int u = 0; u < UNITS; ++u)
        a = fmaf(W_lat[v * UNITS + u], hl[u], a);   // wave-uniform -> s_load
      if (live) outh[i] = tanhf_fast(a);
    }
  }
}

extern "C" void kernel_launch(void* const* d_in, const int* in_sizes, int n_in,
                              void* d_out, int out_size, void* d_ws, size_t ws_size,
                              hipStream_t stream) {
  const float* x     = (const float*)d_in[0];
  const float* h     = (const float*)d_in[1];
  const float* c     = (const float*)d_in[2];
  const float* W_ih  = (const float*)d_in[3];
  const float* W_hh  = (const float*)d_in[4];
  const float* b_ih  = (const float*)d_in[5];
  const float* b_hh  = (const float*)d_in[6];
  const float* W_lat = (const float*)d_in[7];
  float* out = (float*)d_out;

  u16*   frags = (u16*)d_ws;                       // 10*64*8*2 = 10240 B
  float* bias  = (float*)((char*)d_ws + 10240);    // 320 B

  int B = in_sizes[0] / UNITS;
  prep_kernel<<<1, 256, 0, stream>>>(W_ih, W_hh, b_ih, b_hh, frags, bias);
  int grid = (B + 63) / 64;
  stn_main<<<grid, 256, 0, stream>>>(x, h, c, frags, bias, W_lat, out, B);
}

// Round 3
// 204.439 us; speedup vs baseline: 1.4071x; 1.2749x over previous
//
#include <hip/hip_runtime.h>

#define UNITS 20

typedef __attribute__((ext_vector_type(8))) short short8;
typedef __attribute__((ext_vector_type(4))) float floatx4;
typedef unsigned int u32;
typedef unsigned short u16;

__device__ __forceinline__ float rcpf_fast(float x) { return __builtin_amdgcn_rcpf(x); }
__device__ __forceinline__ float sigmoidf_fast(float x) { return rcpf_fast(1.0f + __expf(-x)); }
__device__ __forceinline__ float tanhf_fast(float x) { return 1.0f - 2.0f * rcpf_fast(1.0f + __expf(2.0f * x)); }

__device__ __forceinline__ u32 f2bf(float f) {
  u32 u = __builtin_bit_cast(u32, f);
  u += 0x7fffu + ((u >> 16) & 1u);   // RNE
  return u >> 16;
}
__device__ __forceinline__ u32 pack2(float a, float b) { return f2bf(a) | (f2bf(b) << 16); }

// ---------------------------------------------------------------------------
// Prep: pack A-operand fragments for the TRANSPOSED gemms.
//  gates^T = Wcat . Z^T   (Wcat = [W_ih | W_hh], 80 x 40, K padded to 64)
//    A-frag (16x16x32): lane l holds A[row = l&15][k = (l>>4)*8 + j].
//    Tile t row r is PERMUTED gate row perm(t,r) = (r&3)*20 + (r>>2)*5 + t,
//    so that output acc[t][reg] (lane q,m) = gate[reg*20 + q*5 + t] of batch m.
//  lateral^T = W_lat . Hl^T (20 x 20, K padded to 32), identity row layout.
//  bias4[u] = (bi, bf, bg, bo) for unit u.
// ---------------------------------------------------------------------------
__global__ void prep_kernel(const float* __restrict__ W_ih, const float* __restrict__ W_hh,
                            const float* __restrict__ b_ih, const float* __restrict__ b_hh,
                            const float* __restrict__ W_lat,
                            u16* __restrict__ fragsG, u16* __restrict__ fragsL,
                            float4* __restrict__ bias4) {
  int tid = threadIdx.x;
  for (int e = tid; e < 768; e += 256) {   // 10 gate frags + 2 lateral frags
    int fi = e >> 6, lane = e & 63;
    int r = lane & 15, q = lane >> 4;
    short8 v8;
    if (fi < 10) {
      int t = fi >> 1, cc = fi & 1;
      int gr = (r & 3) * 20 + (r >> 2) * 5 + t;   // permuted gate row
#pragma unroll
      for (int j = 0; j < 8; ++j) {
        int k = cc * 32 + q * 8 + j;
        float v = 0.0f;
        if (k < 20) v = W_ih[gr * UNITS + k];
        else if (k < 40) v = W_hh[gr * UNITS + (k - 20)];
        v8[j] = (short)f2bf(v);
      }
      *(short8*)(fragsG + (size_t)e * 8) = v8;
    } else {
      int t = fi - 10;
      int vr = t * 16 + r;
#pragma unroll
      for (int j = 0; j < 8; ++j) {
        int k = q * 8 + j;
        float v = (vr < 20 && k < 20) ? W_lat[vr * UNITS + k] : 0.0f;
        v8[j] = (short)f2bf(v);
      }
      *(short8*)(fragsL + (size_t)(t * 64 + lane) * 8) = v8;
    }
  }
  if (tid < 20)
    bias4[tid] = make_float4(b_ih[tid] + b_hh[tid],
                             b_ih[20 + tid] + b_hh[20 + tid],
                             b_ih[40 + tid] + b_hh[40 + tid],
                             b_ih[60 + tid] + b_hh[60 + tid]);
}

// ---------------------------------------------------------------------------
// Main: 256 threads = 4 waves; block = 64 batch rows (wave wv owns rows
// wv*16 .. wv*16+15 as the MFMA column/batch dim).
// LDS overlays (19456 B total -> 8 blocks/CU by LDS):
//   [0,9216)      Zs (bf16 [x|h|0], stride 72)   -> later Cn (f32, stride 20)
//   [9216,14336)  Cs (f32 c staged, stride 20)   -> later Hn (f32, stride 20)
//   [14336,19456) Hl (bf16 h_lstm, stride 40, k padded to 32)
// ---------------------------------------------------------------------------
#define SZE 72
#define SHL 40

__global__ __launch_bounds__(256) void stn_main(
    const float* __restrict__ x, const float* __restrict__ h, const float* __restrict__ c,
    const u16* __restrict__ fragsG, const u16* __restrict__ fragsL,
    const float4* __restrict__ bias4, float* __restrict__ out, int B) {
  __shared__ unsigned char smem[19456];
  u16*   Zs = (u16*)smem;
  float* Cn = (float*)smem;
  float* Cs = (float*)(smem + 9216);
  float* Hn = (float*)(smem + 9216);
  u16*   Hl = (u16*)(smem + 14336);

  const int tid  = threadIdx.x;
  const int lane = tid & 63;
  const int wv   = tid >> 6;
  const int m = lane & 15, q = lane >> 4;
  const long rowBase = (long)blockIdx.x * 64;
  const int  myrow = wv * 16 + m;          // batch row within block
  const long f4base = rowBase * 5;         // float4 index of block's region
  const long f4max = (long)B * 5 - 1;

  // ---- stage x,h (bf16) and c (f32), fully coalesced float4 ----
  {
    const float4* x4 = (const float4*)x;
    const float4* h4 = (const float4*)h;
    const float4* c4 = (const float4*)c;
    for (int e = tid; e < 320; e += 256) {
      long gi = f4base + e; if (gi > f4max) gi = f4max;
      int row = e / 5, part = e - row * 5;
      float4 vx = x4[gi];
      u32* zp = (u32*)(Zs + row * SZE + part * 4);
      zp[0] = pack2(vx.x, vx.y); zp[1] = pack2(vx.z, vx.w);
      float4 vh = h4[gi];
      u32* zq = (u32*)(Zs + row * SZE + 20 + part * 4);
      zq[0] = pack2(vh.x, vh.y); zq[1] = pack2(vh.z, vh.w);
      ((float4*)Cs)[e] = c4[gi];
    }
    // zero pads: Zs k=40..63 (12 u32/row), Hl k=20..31 (6 u32/row)
    int r = tid & 63, s = tid >> 6;
    u32* zp = (u32*)(Zs + r * SZE + 40);
    zp[s * 3 + 0] = 0; zp[s * 3 + 1] = 0; zp[s * 3 + 2] = 0;
    u32* hp = (u32*)(Hl + r * SHL + 20);
    hp[s] = 0; if (s < 2) hp[s + 4] = 0;
  }
  __syncthreads();

  // ---- gate GEMM: gates^T = Wcat . Z^T ----
  short8 bfr[2];
#pragma unroll
  for (int cc = 0; cc < 2; ++cc)
    bfr[cc] = *(const short8*)(Zs + myrow * SZE + cc * 32 + q * 8);

  floatx4 acc[5];
#pragma unroll
  for (int t = 0; t < 5; ++t) {
    float4 b4 = bias4[q * 5 + t];
    acc[t] = (floatx4){b4.x, b4.y, b4.z, b4.w};
#pragma unroll
    for (int cc = 0; cc < 2; ++cc) {
      short8 af = *(const short8*)(fragsG + (size_t)((t * 2 + cc) * 64 + lane) * 8);
      acc[t] = __builtin_amdgcn_mfma_f32_16x16x32_bf16(af, bfr[cc], acc[t], 0, 0, 0);
    }
  }

  // ---- LSTM pointwise (all in-lane): acc[t] = {i,f,g,o} of unit u=q*5+t ----
  float cnv[5];
#pragma unroll
  for (int t = 0; t < 5; ++t) {
    int u = q * 5 + t;
    float ig = sigmoidf_fast(acc[t][0]);
    float fg = sigmoidf_fast(acc[t][1]);
    float gg = tanhf_fast(acc[t][2]);
    float og = sigmoidf_fast(acc[t][3]);
    float cv = Cs[myrow * 20 + u];
    float cn = fg * cv + ig * gg;
    cnv[t] = cn;
    Hl[myrow * SHL + u] = (u16)f2bf(og * tanhf_fast(cn));
  }
  __syncthreads();

  // ---- lateral GEMM: out^T = W_lat . Hl^T  (K=32, one MFMA per tile) ----
  short8 bl = *(const short8*)(Hl + myrow * SHL + q * 8);
  floatx4 accL[2];
#pragma unroll
  for (int t = 0; t < 2; ++t) {
    short8 al = *(const short8*)(fragsL + (size_t)(t * 64 + lane) * 8);
    accL[t] = __builtin_amdgcn_mfma_f32_16x16x32_bf16(al, bl, (floatx4){0.f, 0.f, 0.f, 0.f}, 0, 0, 0);
  }

  // ---- write results to overlay LDS (Zs/Cs dead past this barrier) ----
#pragma unroll
  for (int t = 0; t < 5; ++t) Cn[myrow * 20 + q * 5 + t] = cnv[t];
#pragma unroll
  for (int t = 0; t < 2; ++t)
#pragma unroll
    for (int reg = 0; reg < 4; ++reg) {
      int v = t * 16 + q * 4 + reg;
      if (v < 20) Hn[myrow * 20 + v] = tanhf_fast(accL[t][reg]);
    }
  __syncthreads();

  // ---- coalesced float4 stores ----
  {
    float4* outh4 = (float4*)out;
    float4* outc4 = (float4*)(out + (size_t)B * UNITS);
    for (int e = tid; e < 320; e += 256) {
      long gi = f4base + e;
      if (gi <= f4max) {
        outh4[gi] = ((const float4*)Hn)[e];
        outc4[gi] = ((const float4*)Cn)[e];
      }
    }
  }
}

extern "C" void kernel_launch(void* const* d_in, const int* in_sizes, int n_in,
                              void* d_out, int out_size, void* d_ws, size_t ws_size,
                              hipStream_t stream) {
  const float* x     = (const float*)d_in[0];
  const float* h     = (const float*)d_in[1];
  const float* c     = (const float*)d_in[2];
  const float* W_ih  = (const float*)d_in[3];
  const float* W_hh  = (const float*)d_in[4];
  const float* b_ih  = (const float*)d_in[5];
  const float* b_hh  = (const float*)d_in[6];
  const float* W_lat = (const float*)d_in[7];
  float* out = (float*)d_out;

  u16*    fragsG = (u16*)d_ws;                         // 10*64*8*2 = 10240 B
  u16*    fragsL = (u16*)((char*)d_ws + 10240);        //  2*64*8*2 =  2048 B
  float4* bias4  = (float4*)((char*)d_ws + 12288);     //  20*16    =   320 B

  int B = in_sizes[0] / UNITS;
  prep_kernel<<<1, 256, 0, stream>>>(W_ih, W_hh, b_ih, b_hh, W_lat, fragsG, fragsL, bias4);
  int grid = (B + 63) / 64;
  stn_main<<<grid, 256, 0, stream>>>(x, h, c, fragsG, fragsL, bias4, out, B);
}